// Round 6
// baseline (2698.978 us; speedup 1.0000x reference)
//
#include <hip/hip_runtime.h>

typedef unsigned short u16;
typedef unsigned long long u64;
typedef __attribute__((ext_vector_type(8))) short short8;
typedef __attribute__((ext_vector_type(4))) float floatx4;
typedef __attribute__((ext_vector_type(4))) float f32x4;
typedef __attribute__((ext_vector_type(4))) int intx4;

#define LOG2PI_F 1.8378770664093453f

__device__ inline float bf2f(u16 u) { return __uint_as_float(((unsigned)u) << 16); }
__device__ inline u16 f2bf(float f) {
  unsigned u = __float_as_uint(f);
  u += 0x7fff + ((u >> 16) & 1);   // RTNE
  return (u16)(u >> 16);
}
__device__ inline float sigm(float x) {
  float e = __expf(-x);
  return __builtin_amdgcn_rcpf(1.f + e);
}
__device__ inline float tanh_f(float x) {
  float e = __expf(2.f * x);       // inf-safe: rcp(inf)=0 -> 1
  return 1.f - 2.f * __builtin_amdgcn_rcpf(e + 1.f);
}

// ---------------------------------------------------------------- prep: casts / adds / copies
struct PrepArgs {
  const float* src[18];
  const float* src2[18];
  void* dst[18];
  int mode[18];     // 0: f32->bf16, 1: f32+f32->f32, 2: f32 copy
  int n[18];
  int blk0[19];
  int nseg;
};

__global__ __launch_bounds__(256) void k_prep(PrepArgs a) {
  int b = blockIdx.x, s = 0;
  while (s + 1 < a.nseg && b >= a.blk0[s + 1]) ++s;
  int i = (b - a.blk0[s]) * 1024 + threadIdx.x * 4;
  if (i >= a.n[s]) return;
  if (a.mode[s] == 0) {
    f32x4 v = *(const f32x4*)(a.src[s] + i);
    u64 p = (u64)f2bf(v[0]) | ((u64)f2bf(v[1]) << 16)
          | ((u64)f2bf(v[2]) << 32) | ((u64)f2bf(v[3]) << 48);
    *(u64*)((u16*)a.dst[s] + i) = p;
  } else if (a.mode[s] == 1) {
    f32x4 x = *(const f32x4*)(a.src[s] + i);
    f32x4 y = *(const f32x4*)(a.src2[s] + i);
    *(f32x4*)((float*)a.dst[s] + i) = x + y;
  } else {
    *(f32x4*)((float*)a.dst[s] + i) = *(const f32x4*)(a.src[s] + i);
  }
}

// ---------------------------------------------------------------- Whh per-row int8 quantization
// sr = max/(127*127): gate = acc * sr where acc = sum(h_q * w_q), h_q = h*127, w_q = w*127/max.
__global__ __launch_bounds__(256) void k_quant(const float* __restrict__ w0,
                                               const float* __restrict__ w1,
                                               char* __restrict__ q, float* __restrict__ sr) {
  int tid = threadIdx.x, lane = tid & 63;
  int row = blockIdx.x * 4 + (tid >> 6);
  int br = row >> 10, r = row & 1023;
  const float* src = (br ? w1 : w0) + (size_t)r * 256 + lane * 4;
  f32x4 v = *(const f32x4*)src;
  float m = fmaxf(fmaxf(fabsf(v[0]), fabsf(v[1])), fmaxf(fabsf(v[2]), fabsf(v[3])));
#pragma unroll
  for (int o = 32; o >= 1; o >>= 1) m = fmaxf(m, __shfl_xor(m, o));
  float inv = m > 0.f ? 127.f / m : 0.f;
  int pk = 0;
#pragma unroll
  for (int c = 0; c < 4; ++c) {
    int qq = __float2int_rn(v[c] * inv);
    qq = qq > 127 ? 127 : (qq < -127 ? -127 : qq);
    pk |= (qq & 255) << (8 * c);
  }
  *(int*)(q + (size_t)row * 256 + lane * 4) = pk;
  if (lane == 0) sr[row] = m * (1.f / (127.f * 127.f));
}

// ---------------------------------------------------------------- GEMM: C = act(A @ W^T + bias), z = branch
template <int EPI, int AF32>
__global__ __launch_bounds__(256, 2) void k_gemm(
    const void* __restrict__ Agv, const u16* __restrict__ Wg,
    const float* __restrict__ biasP, void* __restrict__ outv,
    int Nn, int K, int relu, int Tseg,
    long az, long wz, long oz) {
  __shared__ u16 As[128][72];
  __shared__ u16 Ws[128][72];
  const int tid = threadIdx.x;
  const int z = blockIdx.z;
  const int bn = blockIdx.x * 128;
  const int bm = blockIdx.y * 128;
  const int w = tid >> 6, lane = tid & 63, lm = lane & 15, lq = lane >> 4;
  const int wr = (w >> 1) * 64, wc = (w & 1) * 64;
  const int tr = tid >> 3, tc = (tid & 7) * 8;

  const u16* Ab = (const u16*)Agv;
  const float* Af = (const float*)Agv;
  const u16* Wb = Wg + (size_t)z * wz;

  floatx4 acc[4][4] = {};

  for (int k0 = 0; k0 < K; k0 += 64) {
    __syncthreads();
#pragma unroll
    for (int rr = 0; rr < 4; ++rr) {
      int row = rr * 32 + tr;
      if (AF32) {
        const float* src = Af + (size_t)z * az + (size_t)(bm + row) * K + k0 + tc;
        f32x4 v0 = *(const f32x4*)src;
        f32x4 v1 = *(const f32x4*)(src + 4);
        short8 sv;
#pragma unroll
        for (int c = 0; c < 4; ++c) { sv[c] = (short)f2bf(v0[c]); sv[4 + c] = (short)f2bf(v1[c]); }
        *(short8*)&As[row][tc] = sv;
      } else {
        *(short8*)&As[row][tc] = *(const short8*)(Ab + (size_t)z * az + (size_t)(bm + row) * K + k0 + tc);
      }
      *(short8*)&Ws[row][tc] = *(const short8*)(Wb + (size_t)(bn + row) * K + k0 + tc);
    }
    __syncthreads();
#pragma unroll
    for (int kk = 0; kk < 2; ++kk) {
      short8 a4[4], b4[4];
#pragma unroll
      for (int i = 0; i < 4; ++i) {
        a4[i] = *(const short8*)&As[wr + i * 16 + lm][kk * 32 + lq * 8];
        b4[i] = *(const short8*)&Ws[wc + i * 16 + lm][kk * 32 + lq * 8];
      }
#pragma unroll
      for (int i = 0; i < 4; ++i)
#pragma unroll
        for (int j = 0; j < 4; ++j)
          acc[i][j] = __builtin_amdgcn_mfma_f32_16x16x32_bf16(a4[i], b4[j], acc[i][j], 0, 0, 0);
    }
  }

#pragma unroll
  for (int i = 0; i < 4; ++i) {
#pragma unroll
    for (int j = 0; j < 4; ++j) {
      int col = bn + wc + j * 16 + lm;
      float bv = biasP[(size_t)z * Nn + col];
      float v[4];
#pragma unroll
      for (int r = 0; r < 4; ++r) {
        float t = acc[i][j][r] + bv;
        v[r] = relu ? fmaxf(t, 0.f) : t;
      }
      int row0l = bm + wr + i * 16 + lq * 4;
      if (EPI == 1) {
        u16* o = (u16*)outv + (size_t)z * oz;
#pragma unroll
        for (int r = 0; r < 4; ++r) o[(size_t)(row0l + r) * Nn + col] = f2bf(v[r]);
      } else {
        int t_l = row0l >> 8;
        int bfull = row0l & 255;
        int bbx = bfull >> 4;
        int mq = (bfull >> 2) & 3;
        u64 p = (u64)f2bf(v[0]) | ((u64)f2bf(v[1]) << 16)
              | ((u64)f2bf(v[2]) << 32) | ((u64)f2bf(v[3]) << 48);
        u16* o = (u16*)outv + (size_t)z * oz;
        size_t idx = ((((size_t)bbx * Tseg + t_l) * 4 + mq) * 1024 + col) * 4;
        *(u64*)(o + idx) = p;
      }
    }
  }
}

// ---------------------------------------------------------------- LayerNorm + relu -> bf16 (feature LN), z-batched
__global__ __launch_bounds__(256) void k_ln_relu(const u16* __restrict__ in,
                                                 const float* __restrict__ lnp,
                                                 u16* __restrict__ out,
                                                 long inz, long outz) {
  int z = blockIdx.y;
  int w = threadIdx.x >> 6, lane = threadIdx.x & 63;
  size_t row = (size_t)blockIdx.x * 4 + w;
  const u16* ip = in + (size_t)z * inz;
  u16* op = out + (size_t)z * outz;
  const float* gw = lnp + (size_t)z * 512;
  const float* gb = gw + 256;
  u64 hv = *(const u64*)(ip + row * 256 + lane * 4);
  float x[4];
#pragma unroll
  for (int c = 0; c < 4; ++c) x[c] = bf2f((u16)(hv >> (16 * c)));
  float s = x[0] + x[1] + x[2] + x[3];
  float q = x[0] * x[0] + x[1] * x[1] + x[2] * x[2] + x[3] * x[3];
#pragma unroll
  for (int o = 32; o >= 1; o >>= 1) { s += __shfl_xor(s, o); q += __shfl_xor(q, o); }
  float mean = s * (1.f / 256.f);
  float var = q * (1.f / 256.f) - mean * mean;
  float rs = rsqrtf(var + 1e-5f);
  u64 p = 0;
#pragma unroll
  for (int c = 0; c < 4; ++c) {
    int k = lane * 4 + c;
    float y = (x[c] - mean) * rs * gw[k] + gb[k];
    y = fmaxf(y, 0.f);
    p |= ((u64)f2bf(y)) << (16 * c);
  }
  *(u64*)(op + row * 256 + lane * 4) = p;
}

// ---------------------------------------------------------------- LSTM scan, int8 fully-resident, 16 waves
// 32 blocks: blockIdx = bb(0..15) + 16*branch; block owns 16 batch rows for all Tseg steps.
// 16 waves; wave w owns gate tiles n = w + 16a (a=0..3): a=0 -> i, 1 -> f, 2 -> g, 3 -> o.
// Hidden unit j = w*16+lm is IDENTICAL across a (256*a == 0 mod 256), so each lane's 4 accs
// are the 4 gates of its 4 cells -> 4 cells/lane (half the 8-wave VALU). Tiles a=0,1 in
// VGPRs (32 regs), a=2,3 in 131KB LDS. Zero weight loads inside the step loop.
struct ScanArgs {
  const u16 *gin0, *gin1;       // [bb][Tseg][4][1024][4] bf16
  const char *whq0, *whq1;      // [1024][256] i8
  const float *sr0, *sr1;       // [1024] f32 row scales (max/127^2)
  const float *h00, *h01, *c00, *c01;   // [256][256] f32
  char *hs0, *hs1;              // [Tseg][16 bb][4096] i8 frag-order
  float *hsv0, *hsv1, *csv0, *csv1;     // [256][256] f32
  const int* done;
  int t0, Tseg;
};

template <int LDSW>
__global__ __launch_bounds__(1024, 1) void k_scan(ScanArgs A) {
  const int bb = blockIdx.x & 15, br = blockIdx.x >> 4;
  const int rb = bb << 4;
  const int tid = threadIdx.x;
  const int w = tid >> 6, lane = tid & 63, lm = lane & 15, lq = lane >> 4;

  extern __shared__ char dsm[];
  char* wl = dsm;                               // [16 waves][2 tiles][4 kk][64 lanes][16B]
  char* hl = dsm + (LDSW ? 131072 : 0);         // [2][4 kk][64 lanes][16B]

  const char* whq = br ? A.whq1 : A.whq0;
  const float* srP = br ? A.sr1 : A.sr0;
  const u16* gin = (br ? A.gin1 : A.gin0) + (size_t)bb * A.Tseg * 16384;
  const float* h0 = br ? A.h01 : A.h00;
  const float* c0 = br ? A.c01 : A.c00;
  char* hs = (br ? A.hs1 : A.hs0) + bb * 4096;
  float* hsv = br ? A.hsv1 : A.hsv0;
  float* csv = br ? A.csv1 : A.csv0;

  // VGPR-resident tiles a=0,1 (32 regs)
  intx4 wreg[2][4];
#pragma unroll
  for (int a = 0; a < 2; ++a)
#pragma unroll
    for (int kk = 0; kk < 4; ++kk)
      wreg[a][kk] = *(const intx4*)(whq + (size_t)((w + 16 * a) * 16 + lm) * 256 + kk * 64 + lq * 16);

  // LDS-resident tiles a=2,3 (frag-order)
  if (LDSW) {
#pragma unroll
    for (int t = 0; t < 2; ++t)
#pragma unroll
      for (int kk = 0; kk < 4; ++kk) {
        intx4 v = *(const intx4*)(whq + (size_t)((w + 16 * (2 + t)) * 16 + lm) * 256 + kk * 64 + lq * 16);
        *(intx4*)&wl[(size_t)w * 8192 + t * 4096 + kk * 1024 + lane * 16] = v;
      }
  }

  // per-gate row scales
  float srw[4];
#pragma unroll
  for (int a = 0; a < 4; ++a) srw[a] = srP[(w + 16 * a) * 16 + lm];

  // c state (f32 regs, whole scan); lane owns rows lq*4+r, hidden j=w*16+lm
  float creg[4];
#pragma unroll
  for (int r = 0; r < 4; ++r)
    creg[r] = c0[(size_t)(rb + lq * 4 + r) * 256 + w * 16 + lm];

  // h0 -> hl buf0 (i8 frag-order); 1024 threads x 4B
  {
    int p0 = tid * 4;
    int kk = p0 >> 10, ln = (p0 >> 4) & 63;
    int m = ln & 15, lqq = ln >> 4, b0 = p0 & 15;
    const float* hp = h0 + (size_t)(rb + m) * 256 + kk * 64 + lqq * 16 + b0;
    int pk = 0;
#pragma unroll
    for (int i2 = 0; i2 < 4; ++i2) {
      int qv = __float2int_rn(hp[i2] * 127.f);
      qv = qv > 127 ? 127 : (qv < -127 ? -127 : qv);
      pk |= (qv & 255) << (8 * i2);
    }
    *(int*)&hl[p0] = pk;
  }
  __syncthreads();

  // prefetch gin/done for first step
  u64 ghold[4];
#pragma unroll
  for (int a = 0; a < 4; ++a)
    ghold[a] = *(const u64*)(gin + ((size_t)lq * 1024 + (w + 16 * a) * 16 + lm) * 4);
  int daN = A.done[(size_t)A.t0 * 256 + rb + lm];
  intx4 dcN = *(const intx4*)(A.done + (size_t)A.t0 * 256 + rb + lq * 4);

  intx4 z4 = {0, 0, 0, 0};

  for (int tl = 0; tl < A.Tseg; ++tl) {
    const int curo = (tl & 1) * 4096, nxto = curo ^ 4096;

    // unpack gin (before prefetch overwrites ghold)
    floatx4 gf[4];
#pragma unroll
    for (int a = 0; a < 4; ++a) {
      u64 g = ghold[a];
      floatx4 v;
      v[0] = bf2f((u16)g); v[1] = bf2f((u16)(g >> 16));
      v[2] = bf2f((u16)(g >> 32)); v[3] = bf2f((u16)(g >> 48));
      gf[a] = v;
    }
    int da = daN;
    intx4 dc = dcN;

    if (tl + 1 < A.Tseg) {
#pragma unroll
      for (int a = 0; a < 4; ++a)
        ghold[a] = *(const u64*)(gin + (((size_t)(tl + 1) * 4 + lq) * 1024 + (w + 16 * a) * 16 + lm) * 4);
      int tn = A.t0 + tl + 1;
      daN = A.done[(size_t)tn * 256 + rb + lm];
      dcN = *(const intx4*)(A.done + (size_t)tn * 256 + rb + lq * 4);
    }

    // A-frags (h i8, masked by done on row lm)
    intx4 af[4];
#pragma unroll
    for (int kk = 0; kk < 4; ++kk) {
      intx4 hv = *(const intx4*)&hl[curo + kk * 1024 + lane * 16];
      af[kk] = da ? z4 : hv;
    }

    intx4 acc[4] = {};
#pragma unroll
    for (int kk = 0; kk < 4; ++kk)
#pragma unroll
      for (int a = 0; a < 2; ++a)
        acc[a] = __builtin_amdgcn_mfma_i32_16x16x64_i8(af[kk], wreg[a][kk], acc[a], 0, 0, 0);
    if (LDSW) {
#pragma unroll
      for (int t = 0; t < 2; ++t)
#pragma unroll
        for (int kk = 0; kk < 4; ++kk) {
          intx4 wv = *(const intx4*)&wl[(size_t)w * 8192 + t * 4096 + kk * 1024 + lane * 16];
          acc[2 + t] = __builtin_amdgcn_mfma_i32_16x16x64_i8(af[kk], wv, acc[2 + t], 0, 0, 0);
        }
    } else {
#pragma unroll
      for (int t = 0; t < 2; ++t)
#pragma unroll
        for (int kk = 0; kk < 4; ++kk) {
          intx4 wv = *(const intx4*)(whq + (size_t)((w + 16 * (2 + t)) * 16 + lm) * 256 + kk * 64 + lq * 16);
          acc[2 + t] = __builtin_amdgcn_mfma_i32_16x16x64_i8(af[kk], wv, acc[2 + t], 0, 0, 0);
        }
    }

    // cell update: 4 cells/lane, gates i/f/g/o = acc[0..3]
#pragma unroll
    for (int r = 0; r < 4; ++r) {
      float cprev = dc[r] ? 0.f : creg[r];
      float ig = sigm(gf[0][r] + (float)acc[0][r] * srw[0]);
      float fg = sigm(gf[1][r] + (float)acc[1][r] * srw[1]);
      float gg = tanh_f(gf[2][r] + (float)acc[2][r] * srw[2]);
      float og = sigm(gf[3][r] + (float)acc[3][r] * srw[3]);
      float cn = fg * cprev + ig * gg;
      creg[r] = cn;
      float hn = og * tanh_f(cn);
      int qv = __float2int_rn(hn * 127.f);
      // frag-order byte scatter: j=w*16+lm -> kk=(w>>2), sub-lane=(w&3)*16 + row
      hl[nxto + (w >> 2) * 1024 + ((w & 3) * 16 + lq * 4 + r) * 16 + lm] = (char)qv;
      if (tl == A.Tseg - 1) {
        size_t idx = (size_t)(rb + lq * 4 + r) * 256 + w * 16 + lm;
        hsv[idx] = hn;
        csv[idx] = cn;
      }
    }
    __syncthreads();
    // coalesced hs dump of the fresh buffer (4KB/block/step)
    *(int*)(hs + (size_t)tl * 65536 + tid * 4) = *(const int*)&hl[nxto + tid * 4];
  }
}

// ---------------------------------------------------------------- heads: LN + policy/value + logprob/entropy
// hs_* are i8 frag-order [Ts][16][4096]; dequant by 1/127.
__global__ __launch_bounds__(256) void k_head(
    const char* __restrict__ hs_a, const char* __restrict__ hs_c,
    const float* __restrict__ a_lnw, const float* __restrict__ a_lnb,
    const float* __restrict__ c_lnw, const float* __restrict__ c_lnb,
    const float* __restrict__ mW, const float* __restrict__ mb,
    const float* __restrict__ logstd, const float* __restrict__ hW,
    const float* __restrict__ hb, const float* __restrict__ action,
    float* __restrict__ lp, float* __restrict__ ent, float* __restrict__ val,
    int row0) {
  __shared__ float smW[16][260];
  __shared__ float shW[256];
  __shared__ float spar[4][256];
  __shared__ float hrow[4][264];
  int tid = threadIdx.x;
  for (int i = tid; i < 4096; i += 256) smW[i >> 8][i & 255] = mW[i];
  shW[tid] = hW[tid];
  spar[0][tid] = a_lnw[tid]; spar[1][tid] = a_lnb[tid];
  spar[2][tid] = c_lnw[tid]; spar[3][tid] = c_lnb[tid];
  __syncthreads();

  int w = tid >> 6, lane = tid & 63, lm = lane & 15, lq = lane >> 4;
  float entc = 0.f;
#pragma unroll
  for (int j = 0; j < 16; ++j) entc += 0.5f + 0.5f * LOG2PI_F + logstd[j];
  float ls = logstd[lm];
  float sd = __expf(ls);
  float mbj = mb[lm];

  int rbase = (blockIdx.x * 4 + w) * 16;
  for (int rr = 0; rr < 16; ++rr) {
    int row = rbase + rr;
    int m = row & 15;
    size_t base = (size_t)(row >> 8) * 65536 + (size_t)((row >> 4) & 15) * 4096;
    int off = (lane >> 4) * 1024 + (m + 16 * ((lane >> 2) & 3)) * 16 + (lane & 3) * 4;
    int va = *(const int*)(hs_a + base + off);
    float x[4];
#pragma unroll
    for (int c = 0; c < 4; ++c) x[c] = (float)((va << (24 - 8 * c)) >> 24) * (1.f / 127.f);
    float s = x[0] + x[1] + x[2] + x[3];
    float q = x[0] * x[0] + x[1] * x[1] + x[2] * x[2] + x[3] * x[3];
#pragma unroll
    for (int o = 32; o >= 1; o >>= 1) { s += __shfl_xor(s, o); q += __shfl_xor(q, o); }
    float mean = s * (1.f / 256.f);
    float rs = rsqrtf(q * (1.f / 256.f) - mean * mean + 1e-5f);
    floatx4 hh;
#pragma unroll
    for (int c = 0; c < 4; ++c) {
      int k = lane * 4 + c;
      hh[c] = (x[c] - mean) * rs * spar[0][k] + spar[1][k];
    }
    *(floatx4*)&hrow[w][lane * 4] = hh;
    float p = 0.f;
#pragma unroll 16
    for (int k2 = 0; k2 < 64; ++k2) {
      int kx = lq * 64 + ((k2 + lq * 16) & 63);
      p = fmaf(hrow[w][kx], smW[lm][kx], p);
    }
    p += __shfl_xor(p, 16);
    p += __shfl_xor(p, 32);
    float meanj = p + mbj;
    float aj = action[(size_t)(row0 + row) * 16 + lm];
    float z = (aj - meanj) / sd;
    float term = -0.5f * z * z - ls - 0.5f * LOG2PI_F;
    term += __shfl_xor(term, 1);
    term += __shfl_xor(term, 2);
    term += __shfl_xor(term, 4);
    term += __shfl_xor(term, 8);
    int vc = *(const int*)(hs_c + base + off);
    float y[4];
#pragma unroll
    for (int c = 0; c < 4; ++c) y[c] = (float)((vc << (24 - 8 * c)) >> 24) * (1.f / 127.f);
    float s2 = y[0] + y[1] + y[2] + y[3];
    float q2 = y[0] * y[0] + y[1] * y[1] + y[2] * y[2] + y[3] * y[3];
#pragma unroll
    for (int o = 32; o >= 1; o >>= 1) { s2 += __shfl_xor(s2, o); q2 += __shfl_xor(q2, o); }
    float mean2 = s2 * (1.f / 256.f);
    float rs2 = rsqrtf(q2 * (1.f / 256.f) - mean2 * mean2 + 1e-5f);
    float pv = 0.f;
#pragma unroll
    for (int c = 0; c < 4; ++c) {
      int k = lane * 4 + c;
      float hc = (y[c] - mean2) * rs2 * spar[2][k] + spar[3][k];
      pv = fmaf(hc, shW[k], pv);
    }
#pragma unroll
    for (int o = 32; o >= 1; o >>= 1) pv += __shfl_xor(pv, o);
    if (lane == 0) {
      lp[row0 + row] = term;
      ent[row0 + row] = entc;
      val[row0 + row] = pv + hb[0];
    }
  }
}

// ---------------------------------------------------------------- host
extern "C" void kernel_launch(void* const* d_in, const int* in_sizes, int n_in,
                              void* d_out, int out_size, void* d_ws, size_t ws_size,
                              hipStream_t stream) {
  const int N = 131072, T = 512;
  const float* x = (const float*)d_in[0];
  const int* done = (const int*)d_in[1];
  const float* h0i[2] = {(const float*)d_in[2], (const float*)d_in[4]};
  const float* c0i[2] = {(const float*)d_in[3], (const float*)d_in[5]};
  const float* action = (const float*)d_in[6];
  const float *W1[2], *b1[2], *W2[2], *b2[2], *flnw[2], *flnb[2];
  const float *Wih[2], *Whh[2], *bih[2], *bhh[2], *lnw[2], *lnb[2];
  for (int br = 0; br < 2; ++br) {
    int o = 7 + br * 12;
    W1[br] = (const float*)d_in[o + 0];  b1[br] = (const float*)d_in[o + 1];
    W2[br] = (const float*)d_in[o + 2];  b2[br] = (const float*)d_in[o + 3];
    flnw[br] = (const float*)d_in[o + 4]; flnb[br] = (const float*)d_in[o + 5];
    Wih[br] = (const float*)d_in[o + 6]; Whh[br] = (const float*)d_in[o + 7];
    bih[br] = (const float*)d_in[o + 8]; bhh[br] = (const float*)d_in[o + 9];
    lnw[br] = (const float*)d_in[o + 10]; lnb[br] = (const float*)d_in[o + 11];
  }
  const float* mW = (const float*)d_in[31];
  const float* mb = (const float*)d_in[32];
  const float* logstd = (const float*)d_in[33];
  const float* hW = (const float*)d_in[34];
  const float* hb = (const float*)d_in[35];

  float* out = (float*)d_out;
  float* o_lp = out;
  float* o_ent = out + N;
  float* o_val = out + 2 * N;
  float* o_ah = out + 3 * N;
  float* o_ac = o_ah + 65536;
  float* o_ch = o_ac + 65536;
  float* o_cc = o_ch + 65536;

  // tier selection (prefer largest segments that fit ws)
  auto rq = [&](long sr2, long st2) -> size_t {
    long Ts = T / st2, Ms = N / sr2;
    size_t s = 0;
    auto al = [&](size_t b) { s += (b + 255) & ~(size_t)255; };
    al(2 * 65536 * 2); al(2 * 131072 * 2); al(2 * 262144 * 2);
    al(2 * 262144); al(2048 * 4);
    al(2 * 1024 * 4); al(2 * 512 * 4); al(2 * 256 * 4); al(1024 * 4);
    al(2 * 65536 * 4); al(2 * 65536 * 4);
    al((size_t)2 * Ms * 512 * 2);
    al((size_t)2 * Ms * 256 * 2);
    al((size_t)2 * N * 256 * 2);
    al((size_t)2 * Ts * 262144 * 2);
    al((size_t)2 * Ts * 65536);
    return s;
  };
  int sr = 16, st = 16;
  const int cand[7][2] = {{1, 1}, {2, 2}, {4, 4}, {4, 8}, {8, 8}, {8, 16}, {16, 16}};
  for (int i = 0; i < 7; ++i)
    if (rq(cand[i][0], cand[i][1]) + ((size_t)4 << 20) <= ws_size) { sr = cand[i][0]; st = cand[i][1]; break; }
  const long Ts = T / st, Ms = N / sr;

  char* pp = (char*)d_ws;
  auto carve = [&](size_t b) -> void* { void* r = pp; pp += (b + 255) & ~(size_t)255; return r; };
  u16* W1b = (u16*)carve(2 * 65536 * 2);
  u16* W2b = (u16*)carve(2 * 131072 * 2);
  u16* Wihb = (u16*)carve(2 * 262144 * 2);
  char* whhq = (char*)carve(2 * 262144);
  float* srowP = (float*)carve(2048 * 4);
  float* bihh = (float*)carve(2 * 1024 * 4);
  float* b1c = (float*)carve(2 * 512 * 4);
  float* b2c = (float*)carve(2 * 256 * 4);
  float* lnp = (float*)carve(1024 * 4);
  float* hsv = (float*)carve(2 * 65536 * 4);
  float* csv = (float*)carve(2 * 65536 * 4);
  u16* h1 = (u16*)carve((size_t)2 * Ms * 512 * 2);
  u16* g2 = (u16*)carve((size_t)2 * Ms * 256 * 2);
  u16* featP = (u16*)carve((size_t)2 * N * 256 * 2);
  u16* ginP = (u16*)carve((size_t)2 * Ts * 262144 * 2);
  char* hsbP = (char*)carve((size_t)2 * Ts * 65536);

  // prep
  PrepArgs pa{};
  int ns = 0, blk = 0;
  auto addseg = [&](const float* s1, const float* s2, void* d, int n, int mode) {
    pa.src[ns] = s1; pa.src2[ns] = s2; pa.dst[ns] = d; pa.mode[ns] = mode; pa.n[ns] = n;
    pa.blk0[ns] = blk; blk += (n + 1023) / 1024; ++ns;
  };
  for (int br = 0; br < 2; ++br) {
    addseg(W1[br], nullptr, W1b + br * 65536, 65536, 0);
    addseg(W2[br], nullptr, W2b + br * 131072, 131072, 0);
    addseg(Wih[br], nullptr, Wihb + br * 262144, 262144, 0);
    addseg(bih[br], bhh[br], bihh + br * 1024, 1024, 1);
    addseg(b1[br], nullptr, b1c + br * 512, 512, 2);
    addseg(b2[br], nullptr, b2c + br * 256, 256, 2);
    addseg(flnw[br], nullptr, lnp + br * 512, 256, 2);
    addseg(flnb[br], nullptr, lnp + br * 512 + 256, 256, 2);
  }
  pa.nseg = ns;
  pa.blk0[ns] = blk;
  k_prep<<<blk, 256, 0, stream>>>(pa);
  k_quant<<<512, 256, 0, stream>>>(Whh[0], Whh[1], whhq, srowP);

  // scan LDS tier: full-resident needs 131072 + 8192 = 139264 B dynamic LDS
  int ldsw = 1;
  if (hipFuncSetAttribute((const void*)&k_scan<1>, hipFuncAttributeMaxDynamicSharedMemorySize,
                          139264) != hipSuccess)
    ldsw = 0;

  // MLP features (row-segmented, branch z-batched)
  for (int s = 0; s < sr; ++s) {
    k_gemm<1, 1><<<dim3(4, Ms / 128, 2), 256, 0, stream>>>(
        x + (size_t)s * Ms * 128, W1b, b1c, h1, 512, 128, 1, 0,
        0L, 65536L, (long)Ms * 512);
    k_gemm<1, 0><<<dim3(2, Ms / 128, 2), 256, 0, stream>>>(
        h1, W2b, b2c, g2, 256, 512, 0, 0,
        (long)Ms * 512, 131072L, (long)Ms * 256);
    k_ln_relu<<<dim3(Ms / 4, 2), 256, 0, stream>>>(
        g2, lnp, featP + (size_t)s * Ms * 256, (long)Ms * 256, (long)N * 256);
  }

  // gin precompute + scan + heads (time-segmented)
  for (int s = 0; s < st; ++s) {
    long t0 = s * Ts;
    k_gemm<2, 0><<<dim3(8, Ts * 2, 2), 256, 0, stream>>>(
        featP + (size_t)t0 * 65536, Wihb, bihh, ginP, 1024, 256, 0, (int)Ts,
        (long)N * 256, 262144L, Ts * 262144L);
    ScanArgs sa;
    sa.gin0 = ginP; sa.gin1 = ginP + Ts * 262144;
    sa.whq0 = whhq; sa.whq1 = whhq + 262144;
    sa.sr0 = srowP; sa.sr1 = srowP + 1024;
    sa.h00 = s ? hsv : h0i[0]; sa.h01 = s ? hsv + 65536 : h0i[1];
    sa.c00 = s ? csv : c0i[0]; sa.c01 = s ? csv + 65536 : c0i[1];
    sa.hs0 = hsbP; sa.hs1 = hsbP + Ts * 65536;
    bool last = (s == st - 1);
    sa.hsv0 = last ? o_ah : hsv; sa.hsv1 = last ? o_ch : hsv + 65536;
    sa.csv0 = last ? o_ac : csv; sa.csv1 = last ? o_cc : csv + 65536;
    sa.done = done; sa.t0 = (int)t0; sa.Tseg = (int)Ts;
    if (ldsw) k_scan<1><<<32, 1024, 139264, stream>>>(sa);
    else      k_scan<0><<<32, 1024, 8192, stream>>>(sa);
    k_head<<<(int)(Ts * 256 / 64), 256, 0, stream>>>(
        hsbP, hsbP + Ts * 65536, lnw[0], lnb[0], lnw[1], lnb[1],
        mW, mb, logstd, hW, hb, action,
        o_lp, o_ent, o_val, (int)(t0 * 256));
  }
}

// Round 7
// 2153.308 us; speedup vs baseline: 1.2534x; 1.2534x over previous
//
#include <hip/hip_runtime.h>

typedef unsigned short u16;
typedef unsigned long long u64;
typedef __attribute__((ext_vector_type(8))) short short8;
typedef __attribute__((ext_vector_type(4))) float floatx4;
typedef __attribute__((ext_vector_type(4))) float f32x4;
typedef __attribute__((ext_vector_type(4))) int intx4;

#define LOG2PI_F 1.8378770664093453f

__device__ inline float bf2f(u16 u) { return __uint_as_float(((unsigned)u) << 16); }
__device__ inline u16 f2bf(float f) {
  unsigned u = __float_as_uint(f);
  u += 0x7fff + ((u >> 16) & 1);   // RTNE
  return (u16)(u >> 16);
}

// ---------------------------------------------------------------- prep: casts / adds / copies
struct PrepArgs {
  const float* src[18];
  const float* src2[18];
  void* dst[18];
  int mode[18];     // 0: f32->bf16, 1: f32+f32->f32, 2: f32 copy
  int n[18];
  int blk0[19];
  int nseg;
};

__global__ __launch_bounds__(256) void k_prep(PrepArgs a) {
  int b = blockIdx.x, s = 0;
  while (s + 1 < a.nseg && b >= a.blk0[s + 1]) ++s;
  int i = (b - a.blk0[s]) * 1024 + threadIdx.x * 4;
  if (i >= a.n[s]) return;
  if (a.mode[s] == 0) {
    f32x4 v = *(const f32x4*)(a.src[s] + i);
    u64 p = (u64)f2bf(v[0]) | ((u64)f2bf(v[1]) << 16)
          | ((u64)f2bf(v[2]) << 32) | ((u64)f2bf(v[3]) << 48);
    *(u64*)((u16*)a.dst[s] + i) = p;
  } else if (a.mode[s] == 1) {
    f32x4 x = *(const f32x4*)(a.src[s] + i);
    f32x4 y = *(const f32x4*)(a.src2[s] + i);
    *(f32x4*)((float*)a.dst[s] + i) = x + y;
  } else {
    *(f32x4*)((float*)a.dst[s] + i) = *(const f32x4*)(a.src[s] + i);
  }
}

// ---------------------------------------------------------------- Whh per-row int8 quantization
// sr = max/(127*127) * sign-fold: -1 for i/f/o gates, +2 for g gate (matches gin epilogue fold).
__global__ __launch_bounds__(256) void k_quant(const float* __restrict__ w0,
                                               const float* __restrict__ w1,
                                               char* __restrict__ q, float* __restrict__ sr) {
  int tid = threadIdx.x, lane = tid & 63;
  int row = blockIdx.x * 4 + (tid >> 6);
  int br = row >> 10, r = row & 1023;
  const float* src = (br ? w1 : w0) + (size_t)r * 256 + lane * 4;
  f32x4 v = *(const f32x4*)src;
  float m = fmaxf(fmaxf(fabsf(v[0]), fabsf(v[1])), fmaxf(fabsf(v[2]), fabsf(v[3])));
#pragma unroll
  for (int o = 32; o >= 1; o >>= 1) m = fmaxf(m, __shfl_xor(m, o));
  float inv = m > 0.f ? 127.f / m : 0.f;
  int pk = 0;
#pragma unroll
  for (int c = 0; c < 4; ++c) {
    int qq = __float2int_rn(v[c] * inv);
    qq = qq > 127 ? 127 : (qq < -127 ? -127 : qq);
    pk |= (qq & 255) << (8 * c);
  }
  *(int*)(q + (size_t)row * 256 + lane * 4) = pk;
  if (lane == 0) {
    float sf = (r >= 512 && r < 768) ? 2.f : -1.f;
    sr[row] = m * (1.f / (127.f * 127.f)) * sf;
  }
}

// ---------------------------------------------------------------- GEMM: C = act(A @ W^T + bias), z = branch
template <int EPI, int AF32>
__global__ __launch_bounds__(256, 2) void k_gemm(
    const void* __restrict__ Agv, const u16* __restrict__ Wg,
    const float* __restrict__ biasP, void* __restrict__ outv,
    int Nn, int K, int relu, int Tseg,
    long az, long wz, long oz) {
  __shared__ u16 As[128][72];
  __shared__ u16 Ws[128][72];
  const int tid = threadIdx.x;
  const int z = blockIdx.z;
  const int bn = blockIdx.x * 128;
  const int bm = blockIdx.y * 128;
  const int w = tid >> 6, lane = tid & 63, lm = lane & 15, lq = lane >> 4;
  const int wr = (w >> 1) * 64, wc = (w & 1) * 64;
  const int tr = tid >> 3, tc = (tid & 7) * 8;

  const u16* Ab = (const u16*)Agv;
  const float* Af = (const float*)Agv;
  const u16* Wb = Wg + (size_t)z * wz;

  floatx4 acc[4][4] = {};

  for (int k0 = 0; k0 < K; k0 += 64) {
    __syncthreads();
#pragma unroll
    for (int rr = 0; rr < 4; ++rr) {
      int row = rr * 32 + tr;
      if (AF32) {
        const float* src = Af + (size_t)z * az + (size_t)(bm + row) * K + k0 + tc;
        f32x4 v0 = *(const f32x4*)src;
        f32x4 v1 = *(const f32x4*)(src + 4);
        short8 sv;
#pragma unroll
        for (int c = 0; c < 4; ++c) { sv[c] = (short)f2bf(v0[c]); sv[4 + c] = (short)f2bf(v1[c]); }
        *(short8*)&As[row][tc] = sv;
      } else {
        *(short8*)&As[row][tc] = *(const short8*)(Ab + (size_t)z * az + (size_t)(bm + row) * K + k0 + tc);
      }
      *(short8*)&Ws[row][tc] = *(const short8*)(Wb + (size_t)(bn + row) * K + k0 + tc);
    }
    __syncthreads();
#pragma unroll
    for (int kk = 0; kk < 2; ++kk) {
      short8 a4[4], b4[4];
#pragma unroll
      for (int i = 0; i < 4; ++i) {
        a4[i] = *(const short8*)&As[wr + i * 16 + lm][kk * 32 + lq * 8];
        b4[i] = *(const short8*)&Ws[wc + i * 16 + lm][kk * 32 + lq * 8];
      }
#pragma unroll
      for (int i = 0; i < 4; ++i)
#pragma unroll
        for (int j = 0; j < 4; ++j)
          acc[i][j] = __builtin_amdgcn_mfma_f32_16x16x32_bf16(a4[i], b4[j], acc[i][j], 0, 0, 0);
    }
  }

#pragma unroll
  for (int i = 0; i < 4; ++i) {
#pragma unroll
    for (int j = 0; j < 4; ++j) {
      int col = bn + wc + j * 16 + lm;
      float bv = biasP[(size_t)z * Nn + col];
      float v[4];
#pragma unroll
      for (int r = 0; r < 4; ++r) {
        float t = acc[i][j][r] + bv;
        v[r] = relu ? fmaxf(t, 0.f) : t;
      }
      int row0l = bm + wr + i * 16 + lq * 4;
      if (EPI == 1) {
        u16* o = (u16*)outv + (size_t)z * oz;
#pragma unroll
        for (int r = 0; r < 4; ++r) o[(size_t)(row0l + r) * Nn + col] = f2bf(v[r]);
      } else {
        // gate-type fold: i/f/o * -1 (sigmoid arg), g * +2 (tanh arg)
        float s = (col >= 512 && col < 768) ? 2.f : -1.f;
        int t_l = row0l >> 8;
        int bfull = row0l & 255;
        int bbx = bfull >> 4;
        int mq = (bfull >> 2) & 3;
        u64 p = (u64)f2bf(v[0] * s) | ((u64)f2bf(v[1] * s) << 16)
              | ((u64)f2bf(v[2] * s) << 32) | ((u64)f2bf(v[3] * s) << 48);
        u16* o = (u16*)outv + (size_t)z * oz;
        size_t idx = ((((size_t)bbx * Tseg + t_l) * 4 + mq) * 1024 + col) * 4;
        *(u64*)(o + idx) = p;
      }
    }
  }
}

// ---------------------------------------------------------------- LayerNorm + relu -> bf16 (feature LN), z-batched
__global__ __launch_bounds__(256) void k_ln_relu(const u16* __restrict__ in,
                                                 const float* __restrict__ lnp,
                                                 u16* __restrict__ out,
                                                 long inz, long outz) {
  int z = blockIdx.y;
  int w = threadIdx.x >> 6, lane = threadIdx.x & 63;
  size_t row = (size_t)blockIdx.x * 4 + w;
  const u16* ip = in + (size_t)z * inz;
  u16* op = out + (size_t)z * outz;
  const float* gw = lnp + (size_t)z * 512;
  const float* gb = gw + 256;
  u64 hv = *(const u64*)(ip + row * 256 + lane * 4);
  float x[4];
#pragma unroll
  for (int c = 0; c < 4; ++c) x[c] = bf2f((u16)(hv >> (16 * c)));
  float s = x[0] + x[1] + x[2] + x[3];
  float q = x[0] * x[0] + x[1] * x[1] + x[2] * x[2] + x[3] * x[3];
#pragma unroll
  for (int o = 32; o >= 1; o >>= 1) { s += __shfl_xor(s, o); q += __shfl_xor(q, o); }
  float mean = s * (1.f / 256.f);
  float var = q * (1.f / 256.f) - mean * mean;
  float rs = rsqrtf(var + 1e-5f);
  u64 p = 0;
#pragma unroll
  for (int c = 0; c < 4; ++c) {
    int k = lane * 4 + c;
    float y = (x[c] - mean) * rs * gw[k] + gb[k];
    y = fmaxf(y, 0.f);
    p |= ((u64)f2bf(y)) << (16 * c);
  }
  *(u64*)(op + row * 256 + lane * 4) = p;
}

// ---------------------------------------------------------------- LSTM scan, int8 resident, 64 blocks x 8 rows
// blockIdx = bb(0..31) + 32*branch; block owns 8 batch rows (rb=bb*8) for all Tseg steps.
// 8 waves; wave w owns gate tiles n = w + 8a (a=0..7; a=2g+u): g-th gate of hidden unit
// j=(w+8u)*16+lm. MFMA M=16 tile is half-padded (rows 8..15 zero). After MFMA, u=1 accs are
// shfl_xor(32)-redistributed so lanes lq<2 update u=0 cells and lq>=2 update u=1 cells ->
// 4 cells/lane, half the per-SIMD cell VALU of the 16-row layout, spread over 64 CUs.
// Whh tiles a=0..3 in VGPRs (64 regs), a=4..7 in 131KB LDS. Zero weight loads in-loop.
struct ScanArgs {
  const u16 *gin0, *gin1;       // [bbx16][Tseg][4 mq][1024][4] bf16 (sign/2x folded)
  const char *whq0, *whq1;      // [1024][256] i8
  const float *sr0, *sr1;       // [1024] f32 row scales (folded)
  const float *h00, *h01, *c00, *c01;   // [256][256] f32
  char *hs0, *hs1;              // [Tseg][16 bbx][4096] i8 frag-order
  float *hsv0, *hsv1, *csv0, *csv1;     // [256][256] f32
  const int* done;
  int t0, Tseg;
};

template <int LDSW>
__global__ __launch_bounds__(512, 2) void k_scan(ScanArgs A) {
  const int bb = blockIdx.x & 31, br = blockIdx.x >> 5;
  const int bbx = bb >> 1, half = bb & 1;
  const int rb = bb << 3;
  const int tid = threadIdx.x;
  const int w = tid >> 6, lane = tid & 63, lm = lane & 15, lq = lane >> 4;
  const int u = lq >> 1;                 // hidden group handled after redistribution
  const int jj = (w + 8 * u) * 16 + lm;  // this lane's hidden unit
  const int rlo = (lq & 1) * 4;          // local row base (0 or 4)
  const int wj = w + 8 * u;
  const int hoff = (wj >> 2) * 1024 + ((wj & 3) * 16 + rlo) * 16 + lm;

  extern __shared__ char dsm[];
  char* wl = dsm;                               // [8 waves][4 tiles][4 kk][64 lanes][16B]
  char* hl = dsm + (LDSW ? 131072 : 0);         // [2][4096] (16-row frame, rows 8..15 zero)

  const char* whq = br ? A.whq1 : A.whq0;
  const float* srP = br ? A.sr1 : A.sr0;
  const u16* gin = (br ? A.gin1 : A.gin0) + (size_t)bbx * A.Tseg * 16384;
  const float* h0 = br ? A.h01 : A.h00;
  const float* c0 = br ? A.c01 : A.c00;
  char* hs = (br ? A.hs1 : A.hs0) + bbx * 4096;
  float* hsv = br ? A.hsv1 : A.hsv0;
  float* csv = br ? A.csv1 : A.csv0;

  // VGPR-resident tiles a=0..3 (64 regs)
  intx4 wreg[4][4];
#pragma unroll
  for (int a = 0; a < 4; ++a)
#pragma unroll
    for (int kk = 0; kk < 4; ++kk)
      wreg[a][kk] = *(const intx4*)(whq + (size_t)((w + 8 * a) * 16 + lm) * 256 + kk * 64 + lq * 16);

  // LDS-resident tiles a=4..7 (frag-order)
  if (LDSW) {
#pragma unroll
    for (int t = 0; t < 4; ++t)
#pragma unroll
      for (int kk = 0; kk < 4; ++kk) {
        intx4 v = *(const intx4*)(whq + (size_t)((w + 8 * (4 + t)) * 16 + lm) * 256 + kk * 64 + lq * 16);
        *(intx4*)&wl[(size_t)w * 16384 + t * 4096 + kk * 1024 + lane * 16] = v;
      }
  }

  // per-gate row scales for this lane's cells (gate rows g*256 + jj, scales pre-folded)
  float srw[4];
#pragma unroll
  for (int g = 0; g < 4; ++g) srw[g] = srP[g * 256 + jj];

  // c state (f32 regs whole scan): rows rb+rlo+r, hidden jj
  float creg[4];
#pragma unroll
  for (int r = 0; r < 4; ++r)
    creg[r] = c0[(size_t)(rb + rlo + r) * 256 + jj];

  // init hl: zero both buffers; h0 (quantized i8) into buf0 rows m<8
  {
    int c = tid & 255, buf = tid >> 8;
    int kk = c >> 6, lqk = (c >> 4) & 3, m = c & 15;
    intx4 val = {0, 0, 0, 0};
    if (buf == 0 && m < 8) {
      const float* hp = h0 + (size_t)(rb + m) * 256 + kk * 64 + lqk * 16;
#pragma unroll
      for (int q4 = 0; q4 < 4; ++q4) {
        int pk = 0;
#pragma unroll
        for (int b = 0; b < 4; ++b) {
          int qv = __float2int_rn(hp[q4 * 4 + b] * 127.f);
          qv = qv > 127 ? 127 : (qv < -127 ? -127 : qv);
          pk |= (qv & 255) << (8 * b);
        }
        val[q4] = pk;
      }
    }
    *(intx4*)&hl[buf * 4096 + c * 16] = val;
  }
  __syncthreads();

  // prefetch gin/done for first step
  const int mq = half * 2 + (lq & 1);
  u64 ghold[4];
#pragma unroll
  for (int g = 0; g < 4; ++g)
    ghold[g] = *(const u64*)(gin + ((size_t)mq * 1024 + g * 256 + jj) * 4);
  int daN = A.done[(size_t)A.t0 * 256 + rb + (lm & 7)];
  intx4 dcN = *(const intx4*)(A.done + (size_t)A.t0 * 256 + rb + rlo);

  intx4 z4 = {0, 0, 0, 0};

  for (int tl = 0; tl < A.Tseg; ++tl) {
    const int curo = (tl & 1) * 4096, nxto = curo ^ 4096;

    floatx4 gf[4];
#pragma unroll
    for (int g = 0; g < 4; ++g) {
      u64 gv = ghold[g];
      floatx4 v;
      v[0] = bf2f((u16)gv); v[1] = bf2f((u16)(gv >> 16));
      v[2] = bf2f((u16)(gv >> 32)); v[3] = bf2f((u16)(gv >> 48));
      gf[g] = v;
    }
    int da = daN;
    intx4 dc = dcN;

    if (tl + 1 < A.Tseg) {
#pragma unroll
      for (int g = 0; g < 4; ++g)
        ghold[g] = *(const u64*)(gin + (((size_t)(tl + 1) * 4 + mq) * 1024 + g * 256 + jj) * 4);
      int tn = A.t0 + tl + 1;
      daN = A.done[(size_t)tn * 256 + rb + (lm & 7)];
      dcN = *(const intx4*)(A.done + (size_t)tn * 256 + rb + rlo);
    }

    // A-frags (h i8, row lm; rows >=8 permanently zero)
    intx4 af[4];
#pragma unroll
    for (int kk = 0; kk < 4; ++kk) {
      intx4 hv = *(const intx4*)&hl[curo + kk * 1024 + lane * 16];
      af[kk] = da ? z4 : hv;
    }

    intx4 acc[8] = {};
#pragma unroll
    for (int kk = 0; kk < 4; ++kk)
#pragma unroll
      for (int a = 0; a < 4; ++a)
        acc[a] = __builtin_amdgcn_mfma_i32_16x16x64_i8(af[kk], wreg[a][kk], acc[a], 0, 0, 0);
    if (LDSW) {
#pragma unroll
      for (int t = 0; t < 4; ++t)
#pragma unroll
        for (int kk = 0; kk < 4; ++kk) {
          intx4 wv = *(const intx4*)&wl[(size_t)w * 16384 + t * 4096 + kk * 1024 + lane * 16];
          acc[4 + t] = __builtin_amdgcn_mfma_i32_16x16x64_i8(af[kk], wv, acc[4 + t], 0, 0, 0);
        }
    } else {
#pragma unroll
      for (int t = 0; t < 4; ++t)
#pragma unroll
        for (int kk = 0; kk < 4; ++kk) {
          intx4 wv = *(const intx4*)(whq + (size_t)((w + 8 * (4 + t)) * 16 + lm) * 256 + kk * 64 + lq * 16);
          acc[4 + t] = __builtin_amdgcn_mfma_i32_16x16x64_i8(af[kk], wv, acc[4 + t], 0, 0, 0);
        }
    }

    // redistribute: tile a=2g+u; u=1 values move lq{0,1}->lq{2,3}
    float av[4][4];
#pragma unroll
    for (int g = 0; g < 4; ++g)
#pragma unroll
      for (int r = 0; r < 4; ++r) {
        int oth = __shfl_xor(acc[2 * g + 1][r], 32);
        av[g][r] = (float)(lq < 2 ? acc[2 * g][r] : oth);
      }

    // cell update: 4 cells/lane. gin & srw pre-folded: i/f/o args = -gate, g arg = 2*gate
#pragma unroll
    for (int r = 0; r < 4; ++r) {
      float cprev = dc[r] ? 0.f : creg[r];
      float xi = fmaf(av[0][r], srw[0], gf[0][r]);
      float xf = fmaf(av[1][r], srw[1], gf[1][r]);
      float xg = fmaf(av[2][r], srw[2], gf[2][r]);
      float xo = fmaf(av[3][r], srw[3], gf[3][r]);
      float ig = __builtin_amdgcn_rcpf(1.f + __expf(xi));          // sigmoid(gate)
      float fg = __builtin_amdgcn_rcpf(1.f + __expf(xf));
      float gg = 1.f - 2.f * __builtin_amdgcn_rcpf(1.f + __expf(xg));  // tanh(gate)
      float og = __builtin_amdgcn_rcpf(1.f + __expf(xo));
      float cn = fg * cprev + ig * gg;
      creg[r] = cn;
      float th = 1.f - 2.f * __builtin_amdgcn_rcpf(1.f + __expf(2.f * cn));
      float hn = og * th;
      int qv = __float2int_rn(hn * 127.f);
      hl[nxto + hoff + r * 16] = (char)qv;
      if (tl == A.Tseg - 1) {
        size_t idx = (size_t)(rb + rlo + r) * 256 + jj;
        hsv[idx] = hn;
        csv[idx] = cn;
      }
    }
    __syncthreads();
    // hs dump: 2KB valid data -> global frame slot (rows at m16 = half*8 + m)
    {
      int idx = tid * 4;
      int kk2 = idx >> 9, i2 = idx & 511;
      int lqk2 = i2 >> 7, m2 = (i2 >> 4) & 7, b2 = i2 & 15;
      int lo = nxto + kk2 * 1024 + lqk2 * 256 + m2 * 16 + b2;
      int go = kk2 * 1024 + lqk2 * 256 + half * 128 + m2 * 16 + b2;
      *(int*)(hs + (size_t)tl * 65536 + go) = *(const int*)&hl[lo];
    }
  }
}

// ---------------------------------------------------------------- heads: LN + policy/value + logprob/entropy
__global__ __launch_bounds__(256) void k_head(
    const char* __restrict__ hs_a, const char* __restrict__ hs_c,
    const float* __restrict__ a_lnw, const float* __restrict__ a_lnb,
    const float* __restrict__ c_lnw, const float* __restrict__ c_lnb,
    const float* __restrict__ mW, const float* __restrict__ mb,
    const float* __restrict__ logstd, const float* __restrict__ hW,
    const float* __restrict__ hb, const float* __restrict__ action,
    float* __restrict__ lp, float* __restrict__ ent, float* __restrict__ val,
    int row0) {
  __shared__ float smW[16][260];
  __shared__ float shW[256];
  __shared__ float spar[4][256];
  __shared__ float hrow[4][264];
  int tid = threadIdx.x;
  for (int i = tid; i < 4096; i += 256) smW[i >> 8][i & 255] = mW[i];
  shW[tid] = hW[tid];
  spar[0][tid] = a_lnw[tid]; spar[1][tid] = a_lnb[tid];
  spar[2][tid] = c_lnw[tid]; spar[3][tid] = c_lnb[tid];
  __syncthreads();

  int w = tid >> 6, lane = tid & 63, lm = lane & 15, lq = lane >> 4;
  float entc = 0.f;
#pragma unroll
  for (int j = 0; j < 16; ++j) entc += 0.5f + 0.5f * LOG2PI_F + logstd[j];
  float ls = logstd[lm];
  float sd = __expf(ls);
  float mbj = mb[lm];

  int rbase = (blockIdx.x * 4 + w) * 16;
  for (int rr = 0; rr < 16; ++rr) {
    int row = rbase + rr;
    int m = row & 15;
    size_t base = (size_t)(row >> 8) * 65536 + (size_t)((row >> 4) & 15) * 4096;
    int off = (lane >> 4) * 1024 + (m + 16 * ((lane >> 2) & 3)) * 16 + (lane & 3) * 4;
    int va = *(const int*)(hs_a + base + off);
    float x[4];
#pragma unroll
    for (int c = 0; c < 4; ++c) x[c] = (float)((va << (24 - 8 * c)) >> 24) * (1.f / 127.f);
    float s = x[0] + x[1] + x[2] + x[3];
    float q = x[0] * x[0] + x[1] * x[1] + x[2] * x[2] + x[3] * x[3];
#pragma unroll
    for (int o = 32; o >= 1; o >>= 1) { s += __shfl_xor(s, o); q += __shfl_xor(q, o); }
    float mean = s * (1.f / 256.f);
    float rs = rsqrtf(q * (1.f / 256.f) - mean * mean + 1e-5f);
    floatx4 hh;
#pragma unroll
    for (int c = 0; c < 4; ++c) {
      int k = lane * 4 + c;
      hh[c] = (x[c] - mean) * rs * spar[0][k] + spar[1][k];
    }
    *(floatx4*)&hrow[w][lane * 4] = hh;
    float p = 0.f;
#pragma unroll 16
    for (int k2 = 0; k2 < 64; ++k2) {
      int kx = lq * 64 + ((k2 + lq * 16) & 63);
      p = fmaf(hrow[w][kx], smW[lm][kx], p);
    }
    p += __shfl_xor(p, 16);
    p += __shfl_xor(p, 32);
    float meanj = p + mbj;
    float aj = action[(size_t)(row0 + row) * 16 + lm];
    float z = (aj - meanj) / sd;
    float term = -0.5f * z * z - ls - 0.5f * LOG2PI_F;
    term += __shfl_xor(term, 1);
    term += __shfl_xor(term, 2);
    term += __shfl_xor(term, 4);
    term += __shfl_xor(term, 8);
    int vc = *(const int*)(hs_c + base + off);
    float y[4];
#pragma unroll
    for (int c = 0; c < 4; ++c) y[c] = (float)((vc << (24 - 8 * c)) >> 24) * (1.f / 127.f);
    float s2 = y[0] + y[1] + y[2] + y[3];
    float q2 = y[0] * y[0] + y[1] * y[1] + y[2] * y[2] + y[3] * y[3];
#pragma unroll
    for (int o = 32; o >= 1; o >>= 1) { s2 += __shfl_xor(s2, o); q2 += __shfl_xor(q2, o); }
    float mean2 = s2 * (1.f / 256.f);
    float rs2 = rsqrtf(q2 * (1.f / 256.f) - mean2 * mean2 + 1e-5f);
    float pv = 0.f;
#pragma unroll
    for (int c = 0; c < 4; ++c) {
      int k = lane * 4 + c;
      float hc = (y[c] - mean2) * rs2 * spar[2][k] + spar[3][k];
      pv = fmaf(hc, shW[k], pv);
    }
#pragma unroll
    for (int o = 32; o >= 1; o >>= 1) pv += __shfl_xor(pv, o);
    if (lane == 0) {
      lp[row0 + row] = term;
      ent[row0 + row] = entc;
      val[row0 + row] = pv + hb[0];
    }
  }
}

// ---------------------------------------------------------------- host
extern "C" void kernel_launch(void* const* d_in, const int* in_sizes, int n_in,
                              void* d_out, int out_size, void* d_ws, size_t ws_size,
                              hipStream_t stream) {
  const int N = 131072, T = 512;
  const float* x = (const float*)d_in[0];
  const int* done = (const int*)d_in[1];
  const float* h0i[2] = {(const float*)d_in[2], (const float*)d_in[4]};
  const float* c0i[2] = {(const float*)d_in[3], (const float*)d_in[5]};
  const float* action = (const float*)d_in[6];
  const float *W1[2], *b1[2], *W2[2], *b2[2], *flnw[2], *flnb[2];
  const float *Wih[2], *Whh[2], *bih[2], *bhh[2], *lnw[2], *lnb[2];
  for (int br = 0; br < 2; ++br) {
    int o = 7 + br * 12;
    W1[br] = (const float*)d_in[o + 0];  b1[br] = (const float*)d_in[o + 1];
    W2[br] = (const float*)d_in[o + 2];  b2[br] = (const float*)d_in[o + 3];
    flnw[br] = (const float*)d_in[o + 4]; flnb[br] = (const float*)d_in[o + 5];
    Wih[br] = (const float*)d_in[o + 6]; Whh[br] = (const float*)d_in[o + 7];
    bih[br] = (const float*)d_in[o + 8]; bhh[br] = (const float*)d_in[o + 9];
    lnw[br] = (const float*)d_in[o + 10]; lnb[br] = (const float*)d_in[o + 11];
  }
  const float* mW = (const float*)d_in[31];
  const float* mb = (const float*)d_in[32];
  const float* logstd = (const float*)d_in[33];
  const float* hW = (const float*)d_in[34];
  const float* hb = (const float*)d_in[35];

  float* out = (float*)d_out;
  float* o_lp = out;
  float* o_ent = out + N;
  float* o_val = out + 2 * N;
  float* o_ah = out + 3 * N;
  float* o_ac = o_ah + 65536;
  float* o_ch = o_ac + 65536;
  float* o_cc = o_ch + 65536;

  // tier selection (prefer largest segments that fit ws)
  auto rq = [&](long sr2, long st2) -> size_t {
    long Ts = T / st2, Ms = N / sr2;
    size_t s = 0;
    auto al = [&](size_t b) { s += (b + 255) & ~(size_t)255; };
    al(2 * 65536 * 2); al(2 * 131072 * 2); al(2 * 262144 * 2);
    al(2 * 262144); al(2048 * 4);
    al(2 * 1024 * 4); al(2 * 512 * 4); al(2 * 256 * 4); al(1024 * 4);
    al(2 * 65536 * 4); al(2 * 65536 * 4);
    al((size_t)2 * Ms * 512 * 2);
    al((size_t)2 * Ms * 256 * 2);
    al((size_t)2 * N * 256 * 2);
    al((size_t)2 * Ts * 262144 * 2);
    al((size_t)2 * Ts * 65536);
    return s;
  };
  int sr = 16, st = 16;
  const int cand[7][2] = {{1, 1}, {2, 2}, {4, 4}, {4, 8}, {8, 8}, {8, 16}, {16, 16}};
  for (int i = 0; i < 7; ++i)
    if (rq(cand[i][0], cand[i][1]) + ((size_t)4 << 20) <= ws_size) { sr = cand[i][0]; st = cand[i][1]; break; }
  const long Ts = T / st, Ms = N / sr;

  char* pp = (char*)d_ws;
  auto carve = [&](size_t b) -> void* { void* r = pp; pp += (b + 255) & ~(size_t)255; return r; };
  u16* W1b = (u16*)carve(2 * 65536 * 2);
  u16* W2b = (u16*)carve(2 * 131072 * 2);
  u16* Wihb = (u16*)carve(2 * 262144 * 2);
  char* whhq = (char*)carve(2 * 262144);
  float* srowP = (float*)carve(2048 * 4);
  float* bihh = (float*)carve(2 * 1024 * 4);
  float* b1c = (float*)carve(2 * 512 * 4);
  float* b2c = (float*)carve(2 * 256 * 4);
  float* lnp = (float*)carve(1024 * 4);
  float* hsv = (float*)carve(2 * 65536 * 4);
  float* csv = (float*)carve(2 * 65536 * 4);
  u16* h1 = (u16*)carve((size_t)2 * Ms * 512 * 2);
  u16* g2 = (u16*)carve((size_t)2 * Ms * 256 * 2);
  u16* featP = (u16*)carve((size_t)2 * N * 256 * 2);
  u16* ginP = (u16*)carve((size_t)2 * Ts * 262144 * 2);
  char* hsbP = (char*)carve((size_t)2 * Ts * 65536);

  // prep
  PrepArgs pa{};
  int ns = 0, blk = 0;
  auto addseg = [&](const float* s1, const float* s2, void* d, int n, int mode) {
    pa.src[ns] = s1; pa.src2[ns] = s2; pa.dst[ns] = d; pa.mode[ns] = mode; pa.n[ns] = n;
    pa.blk0[ns] = blk; blk += (n + 1023) / 1024; ++ns;
  };
  for (int br = 0; br < 2; ++br) {
    addseg(W1[br], nullptr, W1b + br * 65536, 65536, 0);
    addseg(W2[br], nullptr, W2b + br * 131072, 131072, 0);
    addseg(Wih[br], nullptr, Wihb + br * 262144, 262144, 0);
    addseg(bih[br], bhh[br], bihh + br * 1024, 1024, 1);
    addseg(b1[br], nullptr, b1c + br * 512, 512, 2);
    addseg(b2[br], nullptr, b2c + br * 256, 256, 2);
    addseg(flnw[br], nullptr, lnp + br * 512, 256, 2);
    addseg(flnb[br], nullptr, lnp + br * 512 + 256, 256, 2);
  }
  pa.nseg = ns;
  pa.blk0[ns] = blk;
  k_prep<<<blk, 256, 0, stream>>>(pa);
  k_quant<<<512, 256, 0, stream>>>(Whh[0], Whh[1], whhq, srowP);

  // scan LDS tier: full-resident needs 131072 + 8192 = 139264 B dynamic LDS
  int ldsw = 1;
  if (hipFuncSetAttribute((const void*)&k_scan<1>, hipFuncAttributeMaxDynamicSharedMemorySize,
                          139264) != hipSuccess)
    ldsw = 0;

  // MLP features (row-segmented, branch z-batched)
  for (int s = 0; s < sr; ++s) {
    k_gemm<1, 1><<<dim3(4, Ms / 128, 2), 256, 0, stream>>>(
        x + (size_t)s * Ms * 128, W1b, b1c, h1, 512, 128, 1, 0,
        0L, 65536L, (long)Ms * 512);
    k_gemm<1, 0><<<dim3(2, Ms / 128, 2), 256, 0, stream>>>(
        h1, W2b, b2c, g2, 256, 512, 0, 0,
        (long)Ms * 512, 131072L, (long)Ms * 256);
    k_ln_relu<<<dim3(Ms / 4, 2), 256, 0, stream>>>(
        g2, lnp, featP + (size_t)s * Ms * 256, (long)Ms * 256, (long)N * 256);
  }

  // gin precompute + scan + heads (time-segmented)
  for (int s = 0; s < st; ++s) {
    long t0 = s * Ts;
    k_gemm<2, 0><<<dim3(8, Ts * 2, 2), 256, 0, stream>>>(
        featP + (size_t)t0 * 65536, Wihb, bihh, ginP, 1024, 256, 0, (int)Ts,
        (long)N * 256, 262144L, Ts * 262144L);
    ScanArgs sa;
    sa.gin0 = ginP; sa.gin1 = ginP + Ts * 262144;
    sa.whq0 = whhq; sa.whq1 = whhq + 262144;
    sa.sr0 = srowP; sa.sr1 = srowP + 1024;
    sa.h00 = s ? hsv : h0i[0]; sa.h01 = s ? hsv + 65536 : h0i[1];
    sa.c00 = s ? csv : c0i[0]; sa.c01 = s ? csv + 65536 : c0i[1];
    sa.hs0 = hsbP; sa.hs1 = hsbP + Ts * 65536;
    bool last = (s == st - 1);
    sa.hsv0 = last ? o_ah : hsv; sa.hsv1 = last ? o_ch : hsv + 65536;
    sa.csv0 = last ? o_ac : csv; sa.csv1 = last ? o_cc : csv + 65536;
    sa.done = done; sa.t0 = (int)t0; sa.Tseg = (int)Ts;
    if (ldsw) k_scan<1><<<64, 512, 139264, stream>>>(sa);
    else      k_scan<0><<<64, 512, 8192, stream>>>(sa);
    k_head<<<(int)(Ts * 256 / 64), 256, 0, stream>>>(
        hsbP, hsbP + Ts * 65536, lnw[0], lnb[0], lnw[1], lnb[1],
        mW, mb, logstd, hW, hb, action,
        o_lp, o_ent, o_val, (int)(t0 * 256));
  }
}